// Round 3
// baseline (510.924 us; speedup 1.0000x reference)
//
#include <hip/hip_runtime.h>
#include <hip/hip_bf16.h>

// Problem constants (DeformableConv2DLayer: B=4, Cin=64, H=W=128, Cout=64,
// 3x3, stride=1, pad=1, dil=1, DG=1)
#define B_  4
#define CIN 64
#define HH  128
#define WW  128
#define COUT 64
#define KK  9   // 3x3

// ---------------------------------------------------------------------------
// Kernel 1: transpose main conv weight [Cout][Cin][3][3] -> wt[Cin*9][Cout]
// so that per-(c,k) weight rows are contiguous and lane-uniform (s_loads).
// ---------------------------------------------------------------------------
__global__ void transpose_w_kernel(const float* __restrict__ w,
                                   float* __restrict__ wt) {
    int i = blockIdx.x * 256 + threadIdx.x;              // over 64*64*9 = 36864
    if (i >= COUT * CIN * KK) return;
    int o = i / (CIN * KK);
    int r = i - o * (CIN * KK);                           // c*9 + k
    wt[r * COUT + o] = w[i];
}

// ---------------------------------------------------------------------------
// Kernel 2 (v2): offset/mask conv, latency-optimized.
// One thread per output pixel; blockIdx.y = output-channel group (3 groups
// of 9). No LDS, no barriers: 9 direct (L1/L2-hit) taps per input channel,
// 9 independent accumulators. grid = 256x3 blocks of 256 -> 3072 waves.
// Output om[b][27][H][W]; group 2 (mask) gets sigmoid.
// ---------------------------------------------------------------------------
__global__ __launch_bounds__(256, 4)
void offset_conv_kernel(const float* __restrict__ x,
                        const float* __restrict__ ow,
                        const float* __restrict__ ob,
                        float* __restrict__ om) {
    const int g   = blockIdx.y;                          // 0,1,2
    const int pix = blockIdx.x * 256 + threadIdx.x;      // 0..65535
    const int b   = pix >> 14;
    const int ho  = (pix >> 7) & 127;
    const int wo  = pix & 127;

    float acc[9];
#pragma unroll
    for (int j = 0; j < 9; ++j) acc[j] = 0.f;

    const float* xb = x + (size_t)b * CIN * HH * WW;

    // row/col validity + safe (clamped) base offsets, loop-invariant over c
    int   roff[3];
    bool  rv[3], cv[3];
    int   coff[3];
#pragma unroll
    for (int ki = 0; ki < 3; ++ki) {
        int hh = ho - 1 + ki;
        rv[ki]   = (hh >= 0) && (hh < HH);
        roff[ki] = (rv[ki] ? hh : 0) * WW;
        int ww_  = wo - 1 + ki;
        cv[ki]   = (ww_ >= 0) && (ww_ < WW);
        coff[ki] = cv[ki] ? ww_ : 0;
    }

    for (int c = 0; c < CIN; ++c) {
        const float* xc = xb + (size_t)c * HH * WW;
        float v[9];
#pragma unroll
        for (int ki = 0; ki < 3; ++ki)
#pragma unroll
            for (int kj = 0; kj < 3; ++kj) {
                float t = xc[roff[ki] + coff[kj]];
                v[ki * 3 + kj] = (rv[ki] && cv[kj]) ? t : 0.f;
            }

        const float* wg = ow + (size_t)(g * 9) * (CIN * KK) + c * KK;
#pragma unroll
        for (int j = 0; j < 9; ++j)
#pragma unroll
            for (int t = 0; t < 9; ++t)
                acc[j] += v[t] * wg[(size_t)j * (CIN * KK) + t];
    }

    float* omp = om + (((size_t)b * 27 + g * 9) * HH + ho) * WW + wo;
#pragma unroll
    for (int j = 0; j < 9; ++j) {
        float r = acc[j] + ob[g * 9 + j];
        if (g == 2) r = 1.f / (1.f + __expf(-r));        // sigmoid on masks
        omp[(size_t)j * HH * WW] = r;
    }
}

// ---------------------------------------------------------------------------
// Kernel 3 (v2b): deformable aggregation + 64x576 per-pixel matmul.
// One block per (b, ho, wo-half); 256 threads: wo = (t&63)+wh*64,
// og = t>>6 (wave-uniform -> weight rows are scalar loads), 16 Cout each.
// grid = 1024 blocks -> 4096 waves (16/CU).
// bid = b*256 + ho*2 + wh  =>  b = bid>>8   (round-2 bug: was >>9)
// ---------------------------------------------------------------------------
__global__ __launch_bounds__(256, 4)
void dcn_main_kernel(const float* __restrict__ x,
                     const float* __restrict__ wt,   // [Cin*9][Cout]
                     const float* __restrict__ bias,
                     const float* __restrict__ om,   // [B][27][H][W]
                     float* __restrict__ out) {
    int bid = blockIdx.x;                 // b*256 + ho*2 + wh
    int wh  = bid & 1;
    int ho  = (bid >> 1) & 127;
    int b   = bid >> 8;
    int wo  = (threadIdx.x & 63) + wh * 64;
    int og  = __builtin_amdgcn_readfirstlane(threadIdx.x >> 6);  // 0..3

    const float* omp = om + (((size_t)b * 27) * HH + ho) * WW + wo;

    int   cidx[9][4];
    float cwt [9][4];
#pragma unroll
    for (int k = 0; k < 9; ++k) {
        float dy = omp[(size_t)k        * HH * WW];
        float dx = omp[(size_t)(9 + k)  * HH * WW];
        float mk = omp[(size_t)(18 + k) * HH * WW];
        float hf = (float)(ho - 1 + k / 3) + dy;
        float wf = (float)(wo - 1 + k % 3) + dx;
        float h0f = floorf(hf), w0f = floorf(wf);
        float lh = hf - h0f, lw = wf - w0f;
        int h0 = (int)h0f, w0 = (int)w0f;
        int h1 = h0 + 1,   w1 = w0 + 1;
        bool vh0 = (h0 >= 0) && (h0 < HH);
        bool vh1 = (h1 >= 0) && (h1 < HH);
        bool vw0 = (w0 >= 0) && (w0 < WW);
        bool vw1 = (w1 >= 0) && (w1 < WW);
        int ch0 = min(max(h0, 0), HH - 1), ch1 = min(max(h1, 0), HH - 1);
        int cw0 = min(max(w0, 0), WW - 1), cw1 = min(max(w1, 0), WW - 1);
        cidx[k][0] = ch0 * WW + cw0;
        cidx[k][1] = ch0 * WW + cw1;
        cidx[k][2] = ch1 * WW + cw0;
        cidx[k][3] = ch1 * WW + cw1;
        cwt[k][0] = (vh0 && vw0) ? (1.f - lh) * (1.f - lw) * mk : 0.f;
        cwt[k][1] = (vh0 && vw1) ? (1.f - lh) * lw         * mk : 0.f;
        cwt[k][2] = (vh1 && vw0) ? lh         * (1.f - lw) * mk : 0.f;
        cwt[k][3] = (vh1 && vw1) ? lh         * lw         * mk : 0.f;
    }

    float acc[16];
#pragma unroll
    for (int o = 0; o < 16; ++o) acc[o] = 0.f;

    const float* xb  = x + (size_t)b * CIN * HH * WW;
    const float* wto = wt + og * 16;

    for (int c = 0; c < CIN; ++c) {
        const float* xc = xb + (size_t)c * HH * WW;
#pragma unroll
        for (int k = 0; k < 9; ++k) {
            float v = cwt[k][0] * xc[cidx[k][0]]
                    + cwt[k][1] * xc[cidx[k][1]]
                    + cwt[k][2] * xc[cidx[k][2]]
                    + cwt[k][3] * xc[cidx[k][3]];
            const float* wrow = wto + (c * 9 + k) * COUT;   // wave-uniform
#pragma unroll
            for (int o = 0; o < 16; ++o)
                acc[o] += v * wrow[o];
        }
    }

    float* op = out + ((((size_t)b * COUT) + og * 16) * HH + ho) * WW + wo;
#pragma unroll
    for (int o = 0; o < 16; ++o)
        op[(size_t)o * HH * WW] = acc[o] + bias[og * 16 + o];
}

// ---------------------------------------------------------------------------
extern "C" void kernel_launch(void* const* d_in, const int* in_sizes, int n_in,
                              void* d_out, int out_size, void* d_ws, size_t ws_size,
                              hipStream_t stream) {
    const float* x    = (const float*)d_in[0];
    const float* wgt  = (const float*)d_in[1];
    const float* bias = (const float*)d_in[2];
    const float* ow   = (const float*)d_in[3];
    const float* ob   = (const float*)d_in[4];
    float* out = (float*)d_out;

    // workspace layout: wt [Cin*9*Cout] then om [B*27*H*W]
    float* wt = (float*)d_ws;
    float* om = wt + (size_t)CIN * KK * COUT;   // 36864 floats

    transpose_w_kernel<<<(COUT * CIN * KK + 255) / 256, 256, 0, stream>>>(wgt, wt);
    offset_conv_kernel<<<dim3(B_ * HH * WW / 256, 3), 256, 0, stream>>>(x, ow, ob, om);
    dcn_main_kernel<<<B_ * HH * 2, 256, 0, stream>>>(x, wt, bias, om, out);
}

// Round 4
// 140.111 us; speedup vs baseline: 3.6466x; 3.6466x over previous
//
#include <hip/hip_runtime.h>
#include <hip/hip_bf16.h>

// DeformableConv2DLayer: B=4, Cin=64, H=W=128, Cout=64, 3x3, s=1, p=1, DG=1
#define B_   4
#define CIN  64
#define HH   128
#define WW   128
#define COUT 64
#define HW   (HH * WW)          // 16384
#define KK   9
#define KDIM (KK * CIN)         // 576 = 18 K-steps of 32
#define NT_MAIN 4               // 4 n-tiles of 16 -> Cout 64
#define NT_OFF  2               // 2 n-tiles of 16 -> 27 (padded to 32)

typedef float  f32x4  __attribute__((ext_vector_type(4)));
typedef short  short8 __attribute__((ext_vector_type(8)));

union U4 {
    uint4    q;
    uint32_t u[4];
    short8   v;
};

__device__ __forceinline__ unsigned short f2bf_bits(float f) {
    union { __hip_bfloat16 h; unsigned short s; } u;
    u.h = __float2bfloat16(f);
    return u.s;
}
__device__ __forceinline__ float bflo(uint32_t u) { return __uint_as_float(u << 16); }
__device__ __forceinline__ float bfhi(uint32_t u) { return __uint_as_float(u & 0xffff0000u); }

// ---------------------------------------------------------------------------
// Kernel 1: pack weights into MFMA B-fragment order (bf16).
// r = t*32 + (lane>>4)*8 + j, t<18;  k = r>>6, c = r&63 (r = k*64+c order).
// main: wpack[((t*4+nt)*64 + lane)*8 + j] = w[o=nt*16+(lane&15)][c][k]
// off:  wop  [((t*2+nt)*64 + lane)*8 + j] = ow[o<27 ? o : pad0][c][k]
// ---------------------------------------------------------------------------
__global__ void pack_weights_kernel(const float* __restrict__ w,
                                    const float* __restrict__ ow,
                                    __hip_bfloat16* __restrict__ wpack,
                                    __hip_bfloat16* __restrict__ wop) {
    int i = blockIdx.x * 256 + threadIdx.x;       // 0..55295
    if (i < 18 * NT_MAIN * 64 * 8) {
        int j = i & 7, l = (i >> 3) & 63, s = i >> 9;   // s = t*4+nt < 72
        int t = s >> 2, nt = s & 3;
        int r = t * 32 + ((l >> 4) << 3) + j;
        int c = r & 63, k = r >> 6;
        int o = nt * 16 + (l & 15);
        wpack[i] = __float2bfloat16(w[(o * CIN + c) * KK + k]);
    } else {
        int i2 = i - 18 * NT_MAIN * 64 * 8;             // < 18432
        int j = i2 & 7, l = (i2 >> 3) & 63, s = i2 >> 9; // s = t*2+nt < 36
        int t = s >> 1, nt = s & 1;
        int r = t * 32 + ((l >> 4) << 3) + j;
        int c = r & 63, k = r >> 6;
        int o = nt * 16 + (l & 15);
        float v = (o < 27) ? ow[(o * CIN + c) * KK + k] : 0.f;
        wop[i2] = __float2bfloat16(v);
    }
}

// ---------------------------------------------------------------------------
// Kernel 2: x fp32 NCHW -> bf16 NHWC.  thread = (b,h,w); 64 coalesced reads
// (lanes = consecutive w), 8x16B contiguous stores per thread.
// ---------------------------------------------------------------------------
__global__ __launch_bounds__(256)
void to_hwc_kernel(const float* __restrict__ x, __hip_bfloat16* __restrict__ xh) {
    int i = blockIdx.x * 256 + threadIdx.x;       // 0..65535
    int b = i >> 14, hw = i & (HW - 1);
    const float* xp = x + (size_t)b * CIN * HW + hw;
    uint32_t u[32];
#pragma unroll
    for (int c = 0; c < CIN; c += 2) {
        float f0 = xp[(size_t)c * HW];
        float f1 = xp[(size_t)(c + 1) * HW];
        u[c >> 1] = f2bf_bits(f0) | ((uint32_t)f2bf_bits(f1) << 16);
    }
    uint4* dst = (uint4*)(xh + (size_t)i * CIN);
#pragma unroll
    for (int q = 0; q < 8; ++q) dst[q] = ((const uint4*)u)[q];
}

// ---------------------------------------------------------------------------
// Kernel 3: offset/mask conv via MFMA.  Wave = 16-px strip x 32 outputs.
// A-frag: direct bf16x8 load from x_hwc (zero-masked at borders).
// om[b][27][H][W] fp32; oc>=18 sigmoid.
// ---------------------------------------------------------------------------
__global__ __launch_bounds__(256, 4)
void offset_mfma_kernel(const __hip_bfloat16* __restrict__ xh,
                        const __hip_bfloat16* __restrict__ wop,
                        const float* __restrict__ ob,
                        float* __restrict__ om) {
    int bid = blockIdx.x;                  // b*256 + ho*2 + wq
    int b = bid >> 8, ho = (bid >> 1) & 127;
    int l = threadIdx.x & 63, wv = threadIdx.x >> 6;
    int wo0 = (bid & 1) * 64 + wv * 16;
    int p = l & 15, grp = l >> 4;
    int wo = wo0 + p;
    int grp16 = grp << 4;                  // byte offset of 8-ch group

    const char* xb = (const char*)xh + (size_t)b * HW * CIN * 2;

    int vo[9];  uint32_t vm[9];
#pragma unroll
    for (int k = 0; k < 9; ++k) {
        const int ki = k / 3, kj = k % 3;
        int hh = ho - 1 + ki, ww_ = wo - 1 + kj;
        bool v = ((unsigned)hh < (unsigned)HH) && ((unsigned)ww_ < (unsigned)WW);
        int hc = v ? hh : 0, wc = v ? ww_ : 0;
        vo[k] = (hc << 14) + (wc << 7);    // (h*128+w)*128 bytes
        vm[k] = v ? 0xffffffffu : 0u;
    }

    f32x4 acc[NT_OFF] = {};
    const uint4* wp = (const uint4*)wop + l;

#pragma unroll
    for (int k = 0; k < 9; ++k) {
#pragma unroll
        for (int half = 0; half < 2; ++half) {
            const int t = 2 * k + half;
            U4 a;
            a.q = *(const uint4*)(xb + vo[k] + half * 64 + grp16);
#pragma unroll
            for (int q = 0; q < 4; ++q) a.u[q] &= vm[k];
            U4 b0, b1;
            b0.q = wp[(t * 2 + 0) * 64];
            b1.q = wp[(t * 2 + 1) * 64];
            acc[0] = __builtin_amdgcn_mfma_f32_16x16x32_bf16(a.v, b0.v, acc[0], 0, 0, 0);
            acc[1] = __builtin_amdgcn_mfma_f32_16x16x32_bf16(a.v, b1.v, acc[1], 0, 0, 0);
        }
    }

#pragma unroll
    for (int nt = 0; nt < NT_OFF; ++nt) {
        int oc = nt * 16 + (l & 15);
        if (oc < 27) {
            float bv = ob[oc];
            float* op = om + ((size_t)(b * 27 + oc)) * HW + ho * WW + wo0 + grp * 4;
#pragma unroll
            for (int i = 0; i < 4; ++i) {
                float v = acc[nt][i] + bv;
                if (oc >= 18) v = 1.f / (1.f + __expf(-v));
                op[i] = v;
            }
        }
    }
}

// ---------------------------------------------------------------------------
// Kernel 4: main deformable conv via MFMA.
// Wave = 16-px strip x all 64 Cout.  Per K-step: 4 corner uint4 loads,
// fp32 bilinear (mask/validity folded into weights), pack to bf16 A-frag,
// 4 B-frag loads, 4 MFMA.  Epilogue: C/D col=lane&15 (=cout), row=grp*4+i (=px).
// ---------------------------------------------------------------------------
__global__ __launch_bounds__(256, 2)
void dcn_mfma_kernel(const __hip_bfloat16* __restrict__ xh,
                     const __hip_bfloat16* __restrict__ wpack,
                     const float* __restrict__ bias,
                     const float* __restrict__ om,
                     float* __restrict__ out) {
    int bid = blockIdx.x;                  // b*256 + ho*2 + wq
    int b = bid >> 8, ho = (bid >> 1) & 127;
    int l = threadIdx.x & 63, wv = threadIdx.x >> 6;
    int wo0 = (bid & 1) * 64 + wv * 16;
    int p = l & 15, grp = l >> 4;
    int wo = wo0 + p;
    int grp16 = grp << 4;

    const char* xb = (const char*)xh + (size_t)b * HW * CIN * 2;

    // prefetch the 27 offset/mask values for this pixel
    const float* omp = om + (size_t)b * 27 * HW + ho * WW + wo;
    float dyr[9], dxr[9], mkr[9];
#pragma unroll
    for (int k = 0; k < 9; ++k) {
        dyr[k] = omp[(size_t)k * HW];
        dxr[k] = omp[(size_t)(9 + k) * HW];
        mkr[k] = omp[(size_t)(18 + k) * HW];
    }

    f32x4 acc[NT_MAIN] = {};
    const uint4* wp = (const uint4*)wpack + l;

#pragma unroll
    for (int k = 0; k < 9; ++k) {
        const int ki = k / 3, kj = k % 3;
        float hf = (float)(ho - 1 + ki) + dyr[k];
        float wf = (float)(wo - 1 + kj) + dxr[k];
        float h0f = floorf(hf), w0f = floorf(wf);
        float lh = hf - h0f, lw = wf - w0f;
        int h0 = (int)h0f, w0 = (int)w0f;
        int h1 = h0 + 1, w1 = w0 + 1;
        bool vh0 = (unsigned)h0 < (unsigned)HH, vh1 = (unsigned)h1 < (unsigned)HH;
        bool vw0 = (unsigned)w0 < (unsigned)WW, vw1 = (unsigned)w1 < (unsigned)WW;
        int ch0 = min(max(h0, 0), HH - 1), ch1 = min(max(h1, 0), HH - 1);
        int cw0 = min(max(w0, 0), WW - 1), cw1 = min(max(w1, 0), WW - 1);
        int r0 = ch0 << 14, r1 = ch1 << 14, q0 = cw0 << 7, q1 = cw1 << 7;
        int co0 = r0 + q0, co1 = r0 + q1, co2 = r1 + q0, co3 = r1 + q1;
        float mkv = mkr[k];
        float wA = (vh0 && vw0) ? (1.f - lh) * (1.f - lw) * mkv : 0.f;
        float wB = (vh0 && vw1) ? (1.f - lh) * lw * mkv : 0.f;
        float wC = (vh1 && vw0) ? lh * (1.f - lw) * mkv : 0.f;
        float wD = (vh1 && vw1) ? lh * lw * mkv : 0.f;

#pragma unroll
        for (int half = 0; half < 2; ++half) {
            const int t = 2 * k + half;
            const int c0b = half * 64 + grp16;
            U4 u0, u1, u2, u3;
            u0.q = *(const uint4*)(xb + co0 + c0b);
            u1.q = *(const uint4*)(xb + co1 + c0b);
            u2.q = *(const uint4*)(xb + co2 + c0b);
            u3.q = *(const uint4*)(xb + co3 + c0b);
            float f[8];
#pragma unroll
            for (int q = 0; q < 4; ++q) {
                f[2 * q]     = wA * bflo(u0.u[q]) + wB * bflo(u1.u[q])
                             + wC * bflo(u2.u[q]) + wD * bflo(u3.u[q]);
                f[2 * q + 1] = wA * bfhi(u0.u[q]) + wB * bfhi(u1.u[q])
                             + wC * bfhi(u2.u[q]) + wD * bfhi(u3.u[q]);
            }
            U4 a;
#pragma unroll
            for (int q = 0; q < 4; ++q)
                a.u[q] = f2bf_bits(f[2 * q]) | ((uint32_t)f2bf_bits(f[2 * q + 1]) << 16);

            U4 b0, b1, b2, b3;
            b0.q = wp[(t * 4 + 0) * 64];
            b1.q = wp[(t * 4 + 1) * 64];
            b2.q = wp[(t * 4 + 2) * 64];
            b3.q = wp[(t * 4 + 3) * 64];
            acc[0] = __builtin_amdgcn_mfma_f32_16x16x32_bf16(a.v, b0.v, acc[0], 0, 0, 0);
            acc[1] = __builtin_amdgcn_mfma_f32_16x16x32_bf16(a.v, b1.v, acc[1], 0, 0, 0);
            acc[2] = __builtin_amdgcn_mfma_f32_16x16x32_bf16(a.v, b2.v, acc[2], 0, 0, 0);
            acc[3] = __builtin_amdgcn_mfma_f32_16x16x32_bf16(a.v, b3.v, acc[3], 0, 0, 0);
        }
    }

#pragma unroll
    for (int nt = 0; nt < NT_MAIN; ++nt) {
        int oc = nt * 16 + (l & 15);
        float bv = bias[oc];
        float* op = out + ((size_t)(b * COUT + oc)) * HW + ho * WW + wo0 + grp * 4;
#pragma unroll
        for (int i = 0; i < 4; ++i) op[i] = acc[nt][i] + bv;
    }
}

// ---------------------------------------------------------------------------
extern "C" void kernel_launch(void* const* d_in, const int* in_sizes, int n_in,
                              void* d_out, int out_size, void* d_ws, size_t ws_size,
                              hipStream_t stream) {
    const float* x    = (const float*)d_in[0];
    const float* wgt  = (const float*)d_in[1];
    const float* bias = (const float*)d_in[2];
    const float* ow   = (const float*)d_in[3];
    const float* ob   = (const float*)d_in[4];
    float* out = (float*)d_out;

    // workspace: wpack 73728B | wop 36864B | om 7077888B | x_hwc 8388608B
    char* ws = (char*)d_ws;
    __hip_bfloat16* wpack = (__hip_bfloat16*)ws;
    __hip_bfloat16* wop   = (__hip_bfloat16*)(ws + 73728);
    float*          om    = (float*)(ws + 110592);
    __hip_bfloat16* xh    = (__hip_bfloat16*)(ws + 110592 + 7077888);

    pack_weights_kernel<<<216, 256, 0, stream>>>(wgt, ow, wpack, wop);
    to_hwc_kernel<<<B_ * HW / 256, 256, 0, stream>>>(x, xh);
    offset_mfma_kernel<<<B_ * HH * 2, 256, 0, stream>>>(xh, wop, ob, om);
    dcn_mfma_kernel<<<B_ * HH * 2, 256, 0, stream>>>(xh, wpack, bias, om, out);
}

// Round 5
// 132.259 us; speedup vs baseline: 3.8631x; 1.0594x over previous
//
#include <hip/hip_runtime.h>
#include <hip/hip_bf16.h>
#include <hip/hip_fp16.h>

// DeformableConv2DLayer: B=4, Cin=64, H=W=128, Cout=64, 3x3, s=1, p=1, DG=1
#define B_   4
#define CIN  64
#define HH   128
#define WW   128
#define COUT 64
#define HW   (HH * WW)          // 16384
#define KK   9
#define NT_MAIN 4               // 4 n-tiles of 16 -> Cout 64
#define NT_OFF  2               // 2 n-tiles of 16 -> 27 (padded to 32)

typedef float    f32x4 __attribute__((ext_vector_type(4)));
typedef _Float16 f16x8 __attribute__((ext_vector_type(8)));

union U4 {
    uint4     q;
    uint32_t  u[4];
    __half2   h2[4];
    f16x8     v;
};

// ---------------------------------------------------------------------------
// Kernel 1 (prep): blocks 0..255 -> x fp32 NCHW -> fp16 NHWC;
// blocks 256..471 -> pack both weight tensors into MFMA B-fragment order.
// B-frag lane map (16x16x32): n = lane&15, k = t*32 + (lane>>4)*8 + j,
// with K ordered r = tap*64 + c  =>  tap = r>>6, c = r&63.
// ---------------------------------------------------------------------------
__global__ __launch_bounds__(256)
void prep_kernel(const float* __restrict__ x,
                 const float* __restrict__ w,
                 const float* __restrict__ ow,
                 __half* __restrict__ xh,
                 __half* __restrict__ wpack,
                 __half* __restrict__ wop) {
    if (blockIdx.x < 256) {
        int i = blockIdx.x * 256 + threadIdx.x;       // 0..65535 = (b,h,w)
        int b = i >> 14, hw = i & (HW - 1);
        const float* xp = x + (size_t)b * CIN * HW + hw;
        uint32_t u[32];
#pragma unroll
        for (int c = 0; c < CIN; c += 2) {
            __half2 h = __floats2half2_rn(xp[(size_t)c * HW], xp[(size_t)(c + 1) * HW]);
            u[c >> 1] = *(uint32_t*)&h;
        }
        uint4* dst = (uint4*)(xh + (size_t)i * CIN);
#pragma unroll
        for (int q = 0; q < 8; ++q) dst[q] = ((const uint4*)u)[q];
    } else {
        int i = (blockIdx.x - 256) * 256 + threadIdx.x;   // 0..55295
        if (i < 18 * NT_MAIN * 64 * 8) {
            int j = i & 7, l = (i >> 3) & 63, s = i >> 9;   // s = t*4+nt
            int t = s >> 2;
            int r = t * 32 + ((l >> 4) << 3) + j;
            int c = r & 63, k = r >> 6;
            int o = (s & 3) * 16 + (l & 15);
            wpack[i] = __float2half(w[(o * CIN + c) * KK + k]);
        } else {
            int i2 = i - 18 * NT_MAIN * 64 * 8;             // < 18432
            int j = i2 & 7, l = (i2 >> 3) & 63, s = i2 >> 9; // s = t*2+nt
            int t = s >> 1;
            int r = t * 32 + ((l >> 4) << 3) + j;
            int c = r & 63, k = r >> 6;
            int o = (s & 1) * 16 + (l & 15);
            wop[i2] = __float2half((o < 27) ? ow[(o * CIN + c) * KK + k] : 0.f);
        }
    }
}

// ---------------------------------------------------------------------------
// Kernel 2 (fused): offset/mask conv phase + deformable conv phase, one wave
// per 16-px strip. Phase 1 computes this strip's 27 offset-conv outputs via
// MFMA and parks them in per-wave LDS (D row = pixel). Phase 2 reads them
// back (broadcast, conflict-free), does fp16-packed bilinear into A-frags,
// and runs the 64x576 matmul on the matrix pipe. No om global round-trip.
// ---------------------------------------------------------------------------
__global__ __launch_bounds__(256, 4)
void dcn_fused_kernel(const __half* __restrict__ xh,
                      const __half* __restrict__ wop,
                      const float* __restrict__ ob,
                      const __half* __restrict__ wpack,
                      const float* __restrict__ bias,
                      float* __restrict__ out) {
    int bid = blockIdx.x;                  // b*256 + ho*2 + wq
    int b = bid >> 8, ho = (bid >> 1) & 127;
    int l = threadIdx.x & 63, wv = threadIdx.x >> 6;
    int wo0 = (bid & 1) * 64 + wv * 16;
    int p = l & 15, grp = l >> 4;
    int wo = wo0 + p;
    int grp16 = grp << 4;                  // byte offset of lane's 8-ch group

    // [wave][oc][px] fp32; row stride 20 words spreads banks; b32 reads at
    // addr oc*20 + px are 16 consecutive words x 4-way broadcast -> free.
    __shared__ float lom[4][27][20];

    const char* xb = (const char*)xh + (size_t)b * HW * CIN * 2;

    // regular-grid tap addresses + border masks (shared by phase 1)
    int vo[9]; uint32_t vm[9];
#pragma unroll
    for (int k = 0; k < 9; ++k) {
        int hh = ho - 1 + k / 3, ww_ = wo - 1 + k % 3;
        bool v = ((unsigned)hh < (unsigned)HH) && ((unsigned)ww_ < (unsigned)WW);
        vo[k] = ((v ? hh : 0) << 14) + ((v ? ww_ : 0) << 7);   // bytes
        vm[k] = v ? 0xffffffffu : 0u;
    }

    // ---------------- Phase 1: offset/mask conv (27 outputs, N padded 32) --
    {
        f32x4 oacc[NT_OFF] = {};
        const uint4* wpo = (const uint4*)wop + l;
#pragma unroll
        for (int k = 0; k < 9; ++k) {
#pragma unroll
            for (int half = 0; half < 2; ++half) {
                const int t = 2 * k + half;
                U4 a;
                a.q = *(const uint4*)(xb + vo[k] + (half << 6) + grp16);
#pragma unroll
                for (int q = 0; q < 4; ++q) a.u[q] &= vm[k];
                U4 b0, b1;
                b0.q = wpo[(t * 2 + 0) * 64];
                b1.q = wpo[(t * 2 + 1) * 64];
                oacc[0] = __builtin_amdgcn_mfma_f32_16x16x32_f16(a.v, b0.v, oacc[0], 0, 0, 0);
                oacc[1] = __builtin_amdgcn_mfma_f32_16x16x32_f16(a.v, b1.v, oacc[1], 0, 0, 0);
            }
        }
        // D: col = lane&15 (=oc within tile), row = grp*4+i (=px)
#pragma unroll
        for (int nt = 0; nt < NT_OFF; ++nt) {
            int oc = nt * 16 + (l & 15);
            if (oc < 27) {
                float bv = ob[oc];
                f32x4 vals;
#pragma unroll
                for (int i = 0; i < 4; ++i) {
                    float v = oacc[nt][i] + bv;
                    if (oc >= 18) v = 1.f / (1.f + __expf(-v));  // sigmoid mask
                    vals[i] = v;
                }
                *(f32x4*)&lom[wv][oc][grp * 4] = vals;
            }
        }
    }
    __syncthreads();

    // ---------------- Phase 2: deformable gather + 64x576 MFMA -------------
    f32x4 acc[NT_MAIN] = {};
    const uint4* wpm = (const uint4*)wpack + l;

#pragma unroll
    for (int k = 0; k < 9; ++k) {
        float dy = lom[wv][k][p];
        float dx = lom[wv][9 + k][p];
        float mk = lom[wv][18 + k][p];
        float hf = (float)(ho - 1 + k / 3) + dy;
        float wf = (float)(wo - 1 + k % 3) + dx;
        float h0f = floorf(hf), w0f = floorf(wf);
        float lh = hf - h0f, lw = wf - w0f;
        int h0 = (int)h0f, w0 = (int)w0f;
        int h1 = h0 + 1, w1 = w0 + 1;
        bool vh0 = (unsigned)h0 < (unsigned)HH, vh1 = (unsigned)h1 < (unsigned)HH;
        bool vw0 = (unsigned)w0 < (unsigned)WW, vw1 = (unsigned)w1 < (unsigned)WW;
        int ch0 = min(max(h0, 0), HH - 1), ch1 = min(max(h1, 0), HH - 1);
        int cw0 = min(max(w0, 0), WW - 1), cw1 = min(max(w1, 0), WW - 1);
        int r0 = ch0 << 14, r1 = ch1 << 14, q0 = cw0 << 7, q1 = cw1 << 7;
        int co0 = r0 + q0, co1 = r0 + q1, co2 = r1 + q0, co3 = r1 + q1;
        float wA = (vh0 && vw0) ? (1.f - lh) * (1.f - lw) * mk : 0.f;
        float wB = (vh0 && vw1) ? (1.f - lh) * lw * mk : 0.f;
        float wC = (vh1 && vw0) ? lh * (1.f - lw) * mk : 0.f;
        float wD = (vh1 && vw1) ? lh * lw * mk : 0.f;
        __half2 wA2 = __float2half2_rn(wA), wB2 = __float2half2_rn(wB);
        __half2 wC2 = __float2half2_rn(wC), wD2 = __float2half2_rn(wD);

#pragma unroll
        for (int half = 0; half < 2; ++half) {
            const int t = 2 * k + half;
            const int c0b = (half << 6) + grp16;
            U4 u0, u1, u2, u3;
            u0.q = *(const uint4*)(xb + co0 + c0b);
            u1.q = *(const uint4*)(xb + co1 + c0b);
            u2.q = *(const uint4*)(xb + co2 + c0b);
            u3.q = *(const uint4*)(xb + co3 + c0b);
            U4 a;
#pragma unroll
            for (int i = 0; i < 4; ++i)
                a.h2[i] = __hfma2(wD2, u3.h2[i],
                          __hfma2(wC2, u2.h2[i],
                          __hfma2(wB2, u1.h2[i],
                          __hmul2(wA2, u0.h2[i]))));

            U4 b0, b1, b2, b3;
            b0.q = wpm[(t * 4 + 0) * 64];
            b1.q = wpm[(t * 4 + 1) * 64];
            b2.q = wpm[(t * 4 + 2) * 64];
            b3.q = wpm[(t * 4 + 3) * 64];
            acc[0] = __builtin_amdgcn_mfma_f32_16x16x32_f16(a.v, b0.v, acc[0], 0, 0, 0);
            acc[1] = __builtin_amdgcn_mfma_f32_16x16x32_f16(a.v, b1.v, acc[1], 0, 0, 0);
            acc[2] = __builtin_amdgcn_mfma_f32_16x16x32_f16(a.v, b2.v, acc[2], 0, 0, 0);
            acc[3] = __builtin_amdgcn_mfma_f32_16x16x32_f16(a.v, b3.v, acc[3], 0, 0, 0);
        }
    }

    // Epilogue: D col = cout, row = px (= grp*4+i)
#pragma unroll
    for (int nt = 0; nt < NT_MAIN; ++nt) {
        int oc = nt * 16 + (l & 15);
        float bv = bias[oc];
        float* op = out + ((size_t)(b * COUT + oc)) * HW + ho * WW + wo0 + grp * 4;
#pragma unroll
        for (int i = 0; i < 4; ++i) op[i] = acc[nt][i] + bv;
    }
}

// ---------------------------------------------------------------------------
extern "C" void kernel_launch(void* const* d_in, const int* in_sizes, int n_in,
                              void* d_out, int out_size, void* d_ws, size_t ws_size,
                              hipStream_t stream) {
    const float* x    = (const float*)d_in[0];
    const float* wgt  = (const float*)d_in[1];
    const float* bias = (const float*)d_in[2];
    const float* ow   = (const float*)d_in[3];
    const float* ob   = (const float*)d_in[4];
    float* out = (float*)d_out;

    // workspace: wpack 73728B | wop 36864B | xh 8388608B
    char* ws = (char*)d_ws;
    __half* wpack = (__half*)ws;
    __half* wop   = (__half*)(ws + 73728);
    __half* xh    = (__half*)(ws + 73728 + 36864);

    prep_kernel<<<472, 256, 0, stream>>>(x, wgt, ow, xh, wpack, wop);
    dcn_fused_kernel<<<B_ * HH * 2, 256, 0, stream>>>(xh, wop, ob, wpack, bias, out);
}

// Round 6
// 131.665 us; speedup vs baseline: 3.8805x; 1.0045x over previous
//
#include <hip/hip_runtime.h>
#include <hip/hip_bf16.h>
#include <hip/hip_fp16.h>

// DeformableConv2DLayer: B=4, Cin=64, H=W=128, Cout=64, 3x3, s=1, p=1, DG=1
#define B_   4
#define CIN  64
#define HH   128
#define WW   128
#define COUT 64
#define HW   (HH * WW)          // 16384
#define KK   9

typedef float    f32x4 __attribute__((ext_vector_type(4)));
typedef _Float16 f16x8 __attribute__((ext_vector_type(8)));

union U4 {
    uint4     q;
    uint32_t  u[4];
    __half2   h2[4];
    f16x8     v;
};

// ---------------------------------------------------------------------------
// Kernel 1 (prep):
//  blocks 0..2047   : x fp32 NCHW -> fp16 NHWC, thread = (pixel, 8-ch group)
//  blocks 2048..2263: pack both weight tensors into MFMA B-fragment order.
// B-frag lane map (16x16x32): n = lane&15, k-elem = t*32 + (lane>>4)*8 + j,
// with K ordered r = tap*64 + c  =>  tap = r>>6, c = r&63.
// ---------------------------------------------------------------------------
__global__ __launch_bounds__(256)
void prep_kernel(const float* __restrict__ x,
                 const float* __restrict__ w,
                 const float* __restrict__ ow,
                 __half* __restrict__ xh,
                 __half* __restrict__ wpack,
                 __half* __restrict__ wop) {
    if (blockIdx.x < 2048) {
        int i  = blockIdx.x * 256 + threadIdx.x;    // 0..524287
        int cg = i & 7;                              // 8-channel group
        int pix = i >> 3;                            // (b,h,w) 0..65535
        int b = pix >> 14;
        int hw = pix & (HW - 1);
        const float* xp = x + (size_t)b * CIN * HW + hw + (size_t)(cg * 8) * HW;
        uint32_t u[4];
#pragma unroll
        for (int q = 0; q < 4; ++q) {
            __half2 h = __floats2half2_rn(xp[(size_t)(2 * q) * HW],
                                          xp[(size_t)(2 * q + 1) * HW]);
            u[q] = *(uint32_t*)&h;
        }
        *(uint4*)(xh + (size_t)pix * CIN + cg * 8) = *(const uint4*)u;
    } else {
        int i = (blockIdx.x - 2048) * 256 + threadIdx.x;   // 0..55295
        if (i < 18 * 4 * 64 * 8) {
            int j = i & 7, l = (i >> 3) & 63, s = i >> 9;   // s = t*4+nt
            int t = s >> 2;
            int r = t * 32 + ((l >> 4) << 3) + j;
            int c = r & 63, k = r >> 6;
            int o = (s & 3) * 16 + (l & 15);
            wpack[i] = __float2half(w[(o * CIN + c) * KK + k]);
        } else {
            int i2 = i - 18 * 4 * 64 * 8;                   // < 18432
            int j = i2 & 7, l = (i2 >> 3) & 63, s = i2 >> 9; // s = t*2+nt
            int t = s >> 1;
            int r = t * 32 + ((l >> 4) << 3) + j;
            int c = r & 63, k = r >> 6;
            int o = (s & 1) * 16 + (l & 15);
            wop[i2] = __float2half((o < 27) ? ow[(o * CIN + c) * KK + k] : 0.f);
        }
    }
}

// ---------------------------------------------------------------------------
// Fused DCN kernel, one WAVE per block (64 thr), 16-px strip per wave.
// Phase 1: offset/mask conv via MFMA, all 18 A-gathers issued up front.
// Phase 2: deformable conv, software-pipelined depth-2 over the 9 taps:
//   while consuming tap k (16B-gathered corners -> packed-fp16 bilinear ->
//   4 MFMA x 2 halves), tap k+2's addresses are computed and its 8 gathers
//   issued. All arrays statically indexed (full unroll) -> registers.
// ---------------------------------------------------------------------------
struct Tap {
    int c0, c1, c2, c3;               // corner byte offsets into xh image
    __half2 wA, wB, wC, wD;           // bilinear*mask weights (validity-folded)
};

__device__ __forceinline__ Tap calc_tap(const float lom[27][20], int k,
                                        int ho, int wo, int p) {
    float dy = lom[k][p];
    float dx = lom[9 + k][p];
    float mk = lom[18 + k][p];
    float hf = (float)(ho - 1 + k / 3) + dy;
    float wf = (float)(wo - 1 + k % 3) + dx;
    float h0f = floorf(hf), w0f = floorf(wf);
    float lh = hf - h0f, lw = wf - w0f;
    int h0 = (int)h0f, w0 = (int)w0f;
    int h1 = h0 + 1, w1 = w0 + 1;
    bool vh0 = (unsigned)h0 < (unsigned)HH, vh1 = (unsigned)h1 < (unsigned)HH;
    bool vw0 = (unsigned)w0 < (unsigned)WW, vw1 = (unsigned)w1 < (unsigned)WW;
    int ch0 = min(max(h0, 0), HH - 1), ch1 = min(max(h1, 0), HH - 1);
    int cw0 = min(max(w0, 0), WW - 1), cw1 = min(max(w1, 0), WW - 1);
    int r0 = ch0 << 14, r1 = ch1 << 14, q0 = cw0 << 7, q1 = cw1 << 7;
    Tap t;
    t.c0 = r0 + q0; t.c1 = r0 + q1; t.c2 = r1 + q0; t.c3 = r1 + q1;
    float wA = (vh0 && vw0) ? (1.f - lh) * (1.f - lw) * mk : 0.f;
    float wB = (vh0 && vw1) ? (1.f - lh) * lw * mk : 0.f;
    float wC = (vh1 && vw0) ? lh * (1.f - lw) * mk : 0.f;
    float wD = (vh1 && vw1) ? lh * lw * mk : 0.f;
    t.wA = __float2half2_rn(wA); t.wB = __float2half2_rn(wB);
    t.wC = __float2half2_rn(wC); t.wD = __float2half2_rn(wD);
    return t;
}

#define ISSUE(T, R0, R1, R2, R3, R4, R5, R6, R7) do {                    \
    R0.q = *(const uint4*)(xb + (T).c0 + grp16);                          \
    R1.q = *(const uint4*)(xb + (T).c1 + grp16);                          \
    R2.q = *(const uint4*)(xb + (T).c2 + grp16);                          \
    R3.q = *(const uint4*)(xb + (T).c3 + grp16);                          \
    R4.q = *(const uint4*)(xb + (T).c0 + 64 + grp16);                     \
    R5.q = *(const uint4*)(xb + (T).c1 + 64 + grp16);                     \
    R6.q = *(const uint4*)(xb + (T).c2 + 64 + grp16);                     \
    R7.q = *(const uint4*)(xb + (T).c3 + 64 + grp16); } while (0)

#define HALF_MFMA(T, R0, R1, R2, R3, TB)  do {                            \
    U4 a;                                                                 \
    a.h2[0] = __hfma2((T).wD, R3.h2[0], __hfma2((T).wC, R2.h2[0],         \
              __hfma2((T).wB, R1.h2[0], __hmul2((T).wA, R0.h2[0]))));     \
    a.h2[1] = __hfma2((T).wD, R3.h2[1], __hfma2((T).wC, R2.h2[1],         \
              __hfma2((T).wB, R1.h2[1], __hmul2((T).wA, R0.h2[1]))));     \
    a.h2[2] = __hfma2((T).wD, R3.h2[2], __hfma2((T).wC, R2.h2[2],         \
              __hfma2((T).wB, R1.h2[2], __hmul2((T).wA, R0.h2[2]))));     \
    a.h2[3] = __hfma2((T).wD, R3.h2[3], __hfma2((T).wC, R2.h2[3],         \
              __hfma2((T).wB, R1.h2[3], __hmul2((T).wA, R0.h2[3]))));     \
    U4 fb0, fb1, fb2, fb3;                                                \
    fb0.q = wpm[((TB) + 0) * 64]; fb1.q = wpm[((TB) + 1) * 64];           \
    fb2.q = wpm[((TB) + 2) * 64]; fb3.q = wpm[((TB) + 3) * 64];           \
    acc0 = __builtin_amdgcn_mfma_f32_16x16x32_f16(a.v, fb0.v, acc0, 0,0,0);\
    acc1 = __builtin_amdgcn_mfma_f32_16x16x32_f16(a.v, fb1.v, acc1, 0,0,0);\
    acc2 = __builtin_amdgcn_mfma_f32_16x16x32_f16(a.v, fb2.v, acc2, 0,0,0);\
    acc3 = __builtin_amdgcn_mfma_f32_16x16x32_f16(a.v, fb3.v, acc3, 0,0,0);\
} while (0)

#define CONSUME(T, kk_, R0, R1, R2, R3, R4, R5, R6, R7) do {              \
    HALF_MFMA(T, R0, R1, R2, R3, 8 * (kk_));                              \
    HALF_MFMA(T, R4, R5, R6, R7, 8 * (kk_) + 4); } while (0)

__global__ __launch_bounds__(64, 3)
void dcn_fused_kernel(const __half* __restrict__ xh,
                      const __half* __restrict__ wop,
                      const float* __restrict__ ob,
                      const __half* __restrict__ wpack,
                      const float* __restrict__ bias,
                      float* __restrict__ out) {
    // bijective XCD swizzle: 4096 blocks, 512 contiguous per XCD
    int bid = blockIdx.x;
    int swz = (bid & 7) * 512 + (bid >> 3);
    int sub = swz & 7;                    // which 16-px strip in the row
    int row = swz >> 3;
    int ho = row & 127, b = row >> 7;
    int l = threadIdx.x;                  // 0..63 (one wave)
    int p = l & 15, grp = l >> 4;
    int wo0 = sub * 16;
    int wo = wo0 + p;
    int grp16 = grp << 4;                 // byte offset of lane's 8-ch group

    __shared__ float lom[27][20];         // wave-private offset-conv results

    const char* xb = (const char*)xh + (size_t)b * HW * CIN * 2;

    // ---------------- Phase 1: offset/mask conv (N padded to 32) -----------
    {
        int vo[9]; uint32_t vm[9];
#pragma unroll
        for (int k = 0; k < 9; ++k) {
            int hh = ho - 1 + k / 3, ww_ = wo - 1 + k % 3;
            bool v = ((unsigned)hh < (unsigned)HH) && ((unsigned)ww_ < (unsigned)WW);
            vo[k] = ((v ? hh : 0) << 14) + ((v ? ww_ : 0) << 7);
            vm[k] = v ? 0xffffffffu : 0u;
        }
        // issue ALL 18 A-fragment gathers up front (addresses are static)
        U4 pa[18];
#pragma unroll
        for (int t = 0; t < 18; ++t)
            pa[t].q = *(const uint4*)(xb + vo[t >> 1] + ((t & 1) << 6) + grp16);

        f32x4 o0 = {}, o1 = {};
        const uint4* wpo = (const uint4*)wop + l;
#pragma unroll
        for (int t = 0; t < 18; ++t) {
            U4 a = pa[t];
#pragma unroll
            for (int q = 0; q < 4; ++q) a.u[q] &= vm[t >> 1];
            U4 b0, b1;
            b0.q = wpo[(t * 2 + 0) * 64];
            b1.q = wpo[(t * 2 + 1) * 64];
            o0 = __builtin_amdgcn_mfma_f32_16x16x32_f16(a.v, b0.v, o0, 0, 0, 0);
            o1 = __builtin_amdgcn_mfma_f32_16x16x32_f16(a.v, b1.v, o1, 0, 0, 0);
        }
        // D: col = lane&15 (= oc in tile), row = grp*4+i (= pixel)
#pragma unroll
        for (int nt = 0; nt < 2; ++nt) {
            int oc = nt * 16 + (l & 15);
            if (oc < 27) {
                float bv = ob[oc];
                f32x4 vals;
#pragma unroll
                for (int i = 0; i < 4; ++i) {
                    float v = (nt == 0 ? o0[i] : o1[i]) + bv;
                    if (oc >= 18) v = 1.f / (1.f + __expf(-v));
                    vals[i] = v;
                }
                *(f32x4*)&lom[oc][grp * 4] = vals;
            }
        }
    }
    __syncthreads();   // single wave: just orders LDS writes before reads

    // ---------------- Phase 2: pipelined deformable gather + MFMA ----------
    f32x4 acc0 = {}, acc1 = {}, acc2 = {}, acc3 = {};
    const uint4* wpm = (const uint4*)wpack + l;

    Tap tA = calc_tap(lom, 0, ho, wo, p);
    U4 A0, A1, A2, A3, A4, A5, A6, A7;
    ISSUE(tA, A0, A1, A2, A3, A4, A5, A6, A7);
    Tap tB = calc_tap(lom, 1, ho, wo, p);
    U4 B0, B1, B2, B3, B4, B5, B6, B7;
    ISSUE(tB, B0, B1, B2, B3, B4, B5, B6, B7);

#pragma unroll
    for (int k = 0; k < 9; ++k) {
        if ((k & 1) == 0) {
            CONSUME(tA, k, A0, A1, A2, A3, A4, A5, A6, A7);
            if (k + 2 < 9) {
                tA = calc_tap(lom, k + 2, ho, wo, p);
                ISSUE(tA, A0, A1, A2, A3, A4, A5, A6, A7);
            }
        } else {
            CONSUME(tB, k, B0, B1, B2, B3, B4, B5, B6, B7);
            if (k + 2 < 9) {
                tB = calc_tap(lom, k + 2, ho, wo, p);
                ISSUE(tB, B0, B1, B2, B3, B4, B5, B6, B7);
            }
        }
    }

    // Epilogue: D col = cout-in-tile, row = pixel (= grp*4+i)
#pragma unroll
    for (int nt = 0; nt < 4; ++nt) {
        int oc = nt * 16 + (l & 15);
        float bv = bias[oc];
        float* op = out + ((size_t)(b * COUT + oc)) * HW + ho * WW + wo0 + grp * 4;
        f32x4 a = (nt == 0) ? acc0 : (nt == 1) ? acc1 : (nt == 2) ? acc2 : acc3;
#pragma unroll
        for (int i = 0; i < 4; ++i) op[i] = a[i] + bv;
    }
}

// ---------------------------------------------------------------------------
extern "C" void kernel_launch(void* const* d_in, const int* in_sizes, int n_in,
                              void* d_out, int out_size, void* d_ws, size_t ws_size,
                              hipStream_t stream) {
    const float* x    = (const float*)d_in[0];
    const float* wgt  = (const float*)d_in[1];
    const float* bias = (const float*)d_in[2];
    const float* ow   = (const float*)d_in[3];
    const float* ob   = (const float*)d_in[4];
    float* out = (float*)d_out;

    // workspace: wpack 73728B | wop 36864B | xh 8388608B
    char* ws = (char*)d_ws;
    __half* wpack = (__half*)ws;
    __half* wop   = (__half*)(ws + 73728);
    __half* xh    = (__half*)(ws + 73728 + 36864);

    prep_kernel<<<2048 + 216, 256, 0, stream>>>(x, wgt, ow, xh, wpack, wop);
    dcn_fused_kernel<<<B_ * HH * 8, 64, 0, stream>>>(xh, wop, ob, wpack, bias, out);
}

// Round 7
// 131.354 us; speedup vs baseline: 3.8897x; 1.0024x over previous
//
#include <hip/hip_runtime.h>
#include <hip/hip_fp16.h>

// DeformableConv2DLayer: B=4, Cin=64, H=W=128, Cout=64, 3x3, s=1, p=1, DG=1
#define B_   4
#define CIN  64
#define HH   128
#define WW   128
#define COUT 64
#define HW   (HH * WW)          // 16384
#define KK   9

typedef float    f32x4 __attribute__((ext_vector_type(4)));
typedef _Float16 f16x8 __attribute__((ext_vector_type(8)));

union U4 {
    uint4     q;
    uint32_t  u[4];
    __half2   h2[4];
    f16x8     v;
};

// ---------------------------------------------------------------------------
// Prep kernel.
//  blocks 0..2047  : x fp32 NCHW -> fp16 NHWC. cg = blockIdx>>8 so lanes are
//                    consecutive pixels -> coalesced reads (round-5 bug fix).
//  blocks 2048..   : pack weights, K-SPLIT order: frag (h, tap, nt), lane l
//                    holds o = nt*16+(l&15), c = 32h + (l>>4)*8 + j.
// ---------------------------------------------------------------------------
__global__ __launch_bounds__(256)
void prep_kernel(const float* __restrict__ x,
                 const float* __restrict__ w,
                 const float* __restrict__ ow,
                 __half* __restrict__ xh,
                 __half* __restrict__ wpack,
                 __half* __restrict__ wop) {
    if (blockIdx.x < 2048) {
        int cg  = blockIdx.x >> 8;                      // 0..7 channel group
        int pix = (blockIdx.x & 255) * 256 + threadIdx.x;  // 0..65535
        int b = pix >> 14, hw = pix & (HW - 1);
        const float* xp = x + (size_t)b * CIN * HW + (size_t)cg * 8 * HW + hw;
        uint32_t u[4];
#pragma unroll
        for (int q = 0; q < 4; ++q) {
            __half2 h = __floats2half2_rn(xp[(size_t)(2 * q) * HW],
                                          xp[(size_t)(2 * q + 1) * HW]);
            u[q] = *(uint32_t*)&h;
        }
        *(uint4*)(xh + (size_t)pix * CIN + cg * 8) = *(const uint4*)u;
    } else {
        int i = (blockIdx.x - 2048) * 256 + threadIdx.x;   // 0..55295
        if (i < 36864) {                                    // main weights
            int j = i & 7, l = (i >> 3) & 63, fi = i >> 9;  // fi < 72
            int h = fi / 36, rem = fi - h * 36;
            int tap = rem >> 2, nt = rem & 3;
            int o = nt * 16 + (l & 15);
            int c = 32 * h + ((l >> 4) << 3) + j;
            wpack[i] = __float2half(w[(o * CIN + c) * KK + tap]);
        } else {                                            // offset weights
            int i2 = i - 36864;                             // < 18432
            int j = i2 & 7, l = (i2 >> 3) & 63, fi = i2 >> 9; // fi < 36
            int h = fi / 18, rem = fi - h * 18;
            int tap = rem >> 1, nt = rem & 1;
            int o = nt * 16 + (l & 15);
            int c = 32 * h + ((l >> 4) << 3) + j;
            wop[i2] = __float2half((o < 27) ? ow[(o * CIN + c) * KK + tap] : 0.f);
        }
    }
}

// ---------------------------------------------------------------------------
// Tap descriptor: clamped corner byte offsets + validity/mask-folded weights.
// ---------------------------------------------------------------------------
struct TapCW {
    int c0, c1, c2, c3;
    __half2 wA, wB, wC, wD;
};

__device__ __forceinline__ TapCW tap_calc(const float lom[27][20], int k,
                                          int ho, int wo, int p) {
    float dy = lom[k][p], dx = lom[9 + k][p], mk = lom[18 + k][p];
    float hf = (float)(ho - 1 + k / 3) + dy;
    float wf = (float)(wo - 1 + k % 3) + dx;
    float h0f = floorf(hf), w0f = floorf(wf);
    float lh = hf - h0f, lw = wf - w0f;
    int h0 = (int)h0f, w0 = (int)w0f;
    int h1 = h0 + 1, w1 = w0 + 1;
    bool vh0 = (unsigned)h0 < (unsigned)HH, vh1 = (unsigned)h1 < (unsigned)HH;
    bool vw0 = (unsigned)w0 < (unsigned)WW, vw1 = (unsigned)w1 < (unsigned)WW;
    int ch0 = min(max(h0, 0), HH - 1), ch1 = min(max(h1, 0), HH - 1);
    int cw0 = min(max(w0, 0), WW - 1), cw1 = min(max(w1, 0), WW - 1);
    int r0 = ch0 << 14, r1 = ch1 << 14, q0 = cw0 << 7, q1 = cw1 << 7;
    TapCW t;
    t.c0 = r0 + q0; t.c1 = r0 + q1; t.c2 = r1 + q0; t.c3 = r1 + q1;
    float wA = (vh0 && vw0) ? (1.f - lh) * (1.f - lw) * mk : 0.f;
    float wB = (vh0 && vw1) ? (1.f - lh) * lw * mk : 0.f;
    float wC = (vh1 && vw0) ? lh * (1.f - lw) * mk : 0.f;
    float wD = (vh1 && vw1) ? lh * lw * mk : 0.f;
    t.wA = __float2half2_rn(wA); t.wB = __float2half2_rn(wB);
    t.wC = __float2half2_rn(wC); t.wD = __float2half2_rn(wD);
    return t;
}

// ---------------------------------------------------------------------------
// Fused DCN kernel, 128 threads = 2 waves per block; wave h owns channel
// half h (K=288 = one 16x16x32 K-step per tap). Pipeline order per iter k:
// issue Bf(k+1), issue G(k+2)  [sched_barrier]  consume G(k)/Bf(k).
// Global issue order G(k),Bf(k),G(k+1),Bf(k+1),G(k+2): consuming Bf(k) waits
// vmcnt(12), keeping 2 taps of gathers in flight. LDS f32 reduce at the end.
// ---------------------------------------------------------------------------
__global__ __launch_bounds__(128, 3)
void dcn_fused_kernel(const __half* __restrict__ xh,
                      const __half* __restrict__ wop,
                      const float* __restrict__ ob,
                      const __half* __restrict__ wpack,
                      const float* __restrict__ bias,
                      float* __restrict__ out) {
    int bid = blockIdx.x;
    int swz = (bid & 7) * 512 + (bid >> 3);   // bijective XCD swizzle (4096%8==0)
    int sub = swz & 7, row = swz >> 3;
    int ho = row & 127, b = row >> 7;
    int h = threadIdx.x >> 6;                 // channel half (wave id)
    int l = threadIdx.x & 63;
    int p = l & 15, grp = l >> 4;
    int wo0 = sub * 16, wo = wo0 + p;
    int cb = h * 64 + grp * 16;               // byte offset inside pixel's 128B

    __shared__ float redbuf[64][20];          // partials (ph1 rows 0..26) + reduce
    __shared__ float lomF[27][20];            // final offset-conv results

    const char* xbt = (const char*)xh + (size_t)b * HW * CIN * 2 + cb;

    // ---------------- Phase 1: offset/mask conv (K-split, N padded 32) -----
    {
        int vo[9]; uint32_t vm[9];
#pragma unroll
        for (int k = 0; k < 9; ++k) {
            int hh = ho - 1 + k / 3, wq = wo - 1 + k % 3;
            bool v = ((unsigned)hh < (unsigned)HH) && ((unsigned)wq < (unsigned)WW);
            vo[k] = ((v ? hh : 0) << 14) + ((v ? wq : 0) << 7);
            vm[k] = v ? 0xffffffffu : 0u;
        }
        U4 pa[9];
#pragma unroll
        for (int t = 0; t < 9; ++t) pa[t].q = *(const uint4*)(xbt + vo[t]);
        __builtin_amdgcn_sched_barrier(0);

        const uint4* wpo = (const uint4*)wop + l;
        U4 pb[2][2];
#pragma unroll
        for (int t = 0; t < 2; ++t) {
            pb[t][0].q = wpo[((h * 9 + t) * 2 + 0) * 64];
            pb[t][1].q = wpo[((h * 9 + t) * 2 + 1) * 64];
        }
        f32x4 o0 = {}, o1 = {};
#pragma unroll
        for (int t = 0; t < 9; ++t) {
            U4 a = pa[t];
#pragma unroll
            for (int q = 0; q < 4; ++q) a.u[q] &= vm[t];
            o0 = __builtin_amdgcn_mfma_f32_16x16x32_f16(a.v, pb[t & 1][0].v, o0, 0, 0, 0);
            o1 = __builtin_amdgcn_mfma_f32_16x16x32_f16(a.v, pb[t & 1][1].v, o1, 0, 0, 0);
            if (t + 2 < 9) {
                pb[t & 1][0].q = wpo[((h * 9 + t + 2) * 2 + 0) * 64];
                pb[t & 1][1].q = wpo[((h * 9 + t + 2) * 2 + 1) * 64];
            }
        }
        // cross-wave reduce + bias + sigmoid -> lomF
        if (h == 1) {
#pragma unroll
            for (int nt = 0; nt < 2; ++nt) {
                int oc = nt * 16 + (l & 15);
                if (oc < 27) *(f32x4*)&redbuf[oc][grp * 4] = (nt ? o1 : o0);
            }
        }
        __syncthreads();
        if (h == 0) {
#pragma unroll
            for (int nt = 0; nt < 2; ++nt) {
                int oc = nt * 16 + (l & 15);
                if (oc < 27) {
                    f32x4 mine = (nt ? o1 : o0);
                    f32x4 oth = *(const f32x4*)&redbuf[oc][grp * 4];
                    float bv = ob[oc];
                    f32x4 s;
#pragma unroll
                    for (int i = 0; i < 4; ++i) {
                        float v = mine[i] + oth[i] + bv;
                        if (oc >= 18) v = 1.f / (1.f + __expf(-v));
                        s[i] = v;
                    }
                    *(f32x4*)&lomF[oc][grp * 4] = s;
                }
            }
        }
        __syncthreads();
    }

    // ---------------- Phase 2: pipelined deformable gather + MFMA ----------
    f32x4 acc[4] = {};
    const uint4* wpm = (const uint4*)wpack + l;
    U4 g[3][4];                     // gather sets, rotate %3 (2 taps in flight)
    U4 bf[2][4];                    // B-frag sets, rotate %2 (1 tap in flight)
    __half2 wwA[3], wwB[3], wwC[3], wwD[3];

    // prologue: G0, Bf0, G1
    {
        TapCW t0 = tap_calc(lomF, 0, ho, wo, p);
        g[0][0].q = *(const uint4*)(xbt + t0.c0);
        g[0][1].q = *(const uint4*)(xbt + t0.c1);
        g[0][2].q = *(const uint4*)(xbt + t0.c2);
        g[0][3].q = *(const uint4*)(xbt + t0.c3);
        wwA[0] = t0.wA; wwB[0] = t0.wB; wwC[0] = t0.wC; wwD[0] = t0.wD;
#pragma unroll
        for (int nt = 0; nt < 4; ++nt)
            bf[0][nt].q = wpm[((h * 9 + 0) * 4 + nt) * 64];
        TapCW t1 = tap_calc(lomF, 1, ho, wo, p);
        g[1][0].q = *(const uint4*)(xbt + t1.c0);
        g[1][1].q = *(const uint4*)(xbt + t1.c1);
        g[1][2].q = *(const uint4*)(xbt + t1.c2);
        g[1][3].q = *(const uint4*)(xbt + t1.c3);
        wwA[1] = t1.wA; wwB[1] = t1.wB; wwC[1] = t1.wC; wwD[1] = t1.wD;
    }
    __builtin_amdgcn_sched_barrier(0);

#pragma unroll
    for (int k = 0; k < 9; ++k) {
        const int sg = k % 3, sb = k & 1;
        if (k + 1 < 9) {            // issue Bf(k+1) BEFORE G(k+2): keeps order
#pragma unroll
            for (int nt = 0; nt < 4; ++nt)
                bf[(k + 1) & 1][nt].q = wpm[((h * 9 + (k + 1)) * 4 + nt) * 64];
        }
        if (k + 2 < 9) {            // issue G(k+2)
            const int sn = (k + 2) % 3;
            TapCW tc = tap_calc(lomF, k + 2, ho, wo, p);
            g[sn][0].q = *(const uint4*)(xbt + tc.c0);
            g[sn][1].q = *(const uint4*)(xbt + tc.c1);
            g[sn][2].q = *(const uint4*)(xbt + tc.c2);
            g[sn][3].q = *(const uint4*)(xbt + tc.c3);
            wwA[sn] = tc.wA; wwB[sn] = tc.wB; wwC[sn] = tc.wC; wwD[sn] = tc.wD;
        }
        __builtin_amdgcn_sched_barrier(0);
        // consume tap k: bilinear -> A-frag, 4 MFMA
        U4 a;
#pragma unroll
        for (int i = 0; i < 4; ++i)
            a.h2[i] = __hfma2(wwD[sg], g[sg][3].h2[i],
                      __hfma2(wwC[sg], g[sg][2].h2[i],
                      __hfma2(wwB[sg], g[sg][1].h2[i],
                      __hmul2(wwA[sg], g[sg][0].h2[i]))));
        acc[0] = __builtin_amdgcn_mfma_f32_16x16x32_f16(a.v, bf[sb][0].v, acc[0], 0, 0, 0);
        acc[1] = __builtin_amdgcn_mfma_f32_16x16x32_f16(a.v, bf[sb][1].v, acc[1], 0, 0, 0);
        acc[2] = __builtin_amdgcn_mfma_f32_16x16x32_f16(a.v, bf[sb][2].v, acc[2], 0, 0, 0);
        acc[3] = __builtin_amdgcn_mfma_f32_16x16x32_f16(a.v, bf[sb][3].v, acc[3], 0, 0, 0);
    }

    // ---------------- Reduce across the two waves + store ------------------
    if (h == 1) {
#pragma unroll
        for (int nt = 0; nt < 4; ++nt) {
            int oc = nt * 16 + (l & 15);
            *(f32x4*)&redbuf[oc][grp * 4] = acc[nt];
        }
    }
    __syncthreads();
    if (h == 0) {
#pragma unroll
        for (int nt = 0; nt < 4; ++nt) {
            int oc = nt * 16 + (l & 15);
            f32x4 oth = *(const f32x4*)&redbuf[oc][grp * 4];
            float bv = bias[oc];
            f32x4 s;
#pragma unroll
            for (int i = 0; i < 4; ++i) s[i] = acc[nt][i] + oth[i] + bv;
            *(f32x4*)(out + ((size_t)(b * COUT + oc)) * HW + ho * WW + wo0 + grp * 4) = s;
        }
    }
}

// ---------------------------------------------------------------------------
extern "C" void kernel_launch(void* const* d_in, const int* in_sizes, int n_in,
                              void* d_out, int out_size, void* d_ws, size_t ws_size,
                              hipStream_t stream) {
    const float* x    = (const float*)d_in[0];
    const float* wgt  = (const float*)d_in[1];
    const float* bias = (const float*)d_in[2];
    const float* ow   = (const float*)d_in[3];
    const float* ob   = (const float*)d_in[4];
    float* out = (float*)d_out;

    // workspace: wpack 73728B | wop 36864B | xh 8388608B
    char* ws = (char*)d_ws;
    __half* wpack = (__half*)ws;
    __half* wop   = (__half*)(ws + 73728);
    __half* xh    = (__half*)(ws + 73728 + 36864);

    prep_kernel<<<2048 + 216, 256, 0, stream>>>(x, wgt, ow, xh, wpack, wop);
    dcn_fused_kernel<<<B_ * HH * 8, 128, 0, stream>>>(xh, wop, ob, wpack, bias, out);
}

// Round 8
// 100.048 us; speedup vs baseline: 5.1068x; 1.3129x over previous
//
#include <hip/hip_runtime.h>
#include <hip/hip_fp16.h>

// DeformableConv2DLayer: B=4, Cin=64, H=W=128, Cout=64, 3x3, s=1, p=1, DG=1
#define B_   4
#define CIN  64
#define HH   128
#define WW   128
#define COUT 64
#define HW   (HH * WW)          // 16384
#define KK   9

typedef float    f32x4 __attribute__((ext_vector_type(4)));
typedef _Float16 f16x8 __attribute__((ext_vector_type(8)));

union U4 {
    uint4     q;
    uint32_t  u[4];
    __half2   h2[4];
    f16x8     v;
};

#define MFMA16(a, b, c) __builtin_amdgcn_mfma_f32_16x16x32_f16((a).v, (b).v, (c), 0, 0, 0)

// ---------------------------------------------------------------------------
// Prep kernel (proven r5/r6 version).
//  blocks 0..2047  : x fp32 NCHW -> fp16 NHWC (lanes = consecutive pixels).
//  blocks 2048..   : pack weights into MFMA B-frag order: frag (t, nt),
//  lane l: o = nt*16+(l&15), K-elem r = t*32+(l>>4)*8+j, tap = r>>6, c = r&63.
// ---------------------------------------------------------------------------
__global__ __launch_bounds__(256)
void prep_kernel(const float* __restrict__ x,
                 const float* __restrict__ w,
                 const float* __restrict__ ow,
                 __half* __restrict__ xh,
                 __half* __restrict__ wpack,
                 __half* __restrict__ wop) {
    if (blockIdx.x < 2048) {
        int cg  = blockIdx.x >> 8;                         // 0..7 channel group
        int pix = (blockIdx.x & 255) * 256 + threadIdx.x;  // 0..65535
        int b = pix >> 14, hw = pix & (HW - 1);
        const float* xp = x + (size_t)b * CIN * HW + (size_t)cg * 8 * HW + hw;
        uint32_t u[4];
#pragma unroll
        for (int q = 0; q < 4; ++q) {
            __half2 h = __floats2half2_rn(xp[(size_t)(2 * q) * HW],
                                          xp[(size_t)(2 * q + 1) * HW]);
            u[q] = *(uint32_t*)&h;
        }
        *(uint4*)(xh + (size_t)pix * CIN + cg * 8) = *(const uint4*)u;
    } else {
        int i = (blockIdx.x - 2048) * 256 + threadIdx.x;   // 0..55295
        if (i < 36864) {                                   // main weights
            int j = i & 7, l = (i >> 3) & 63, s = i >> 9;  // s = t*4+nt
            int t = s >> 2;
            int rr = t * 32 + ((l >> 4) << 3) + j;
            int c = rr & 63, k = rr >> 6;
            int o = (s & 3) * 16 + (l & 15);
            wpack[i] = __float2half(w[(o * CIN + c) * KK + k]);
        } else {                                           // offset weights
            int i2 = i - 36864;                            // < 18432
            int j = i2 & 7, l = (i2 >> 3) & 63, s = i2 >> 9; // s = t*2+nt
            int t = s >> 1;
            int rr = t * 32 + ((l >> 4) << 3) + j;
            int c = rr & 63, k = rr >> 6;
            int o = (s & 1) * 16 + (l & 15);
            wop[i2] = __float2half((o < 27) ? ow[(o * CIN + c) * KK + k] : 0.f);
        }
    }
}

// ---------------------------------------------------------------------------
// Fused DCN kernel. Block = 512 thr = 8 waves = 2 output rows x 128 cols.
// LDS-stages the x window: rows clamp(ho0-3 .. ho0+4) x all 128 cols x 128B,
// XOR-swizzled (pixel stride 128B would otherwise collide banks). All
// phase-1 taps and phase-2 bilinear corners read from LDS; per-tap
// wave-uniform window check with global fallback keeps arbitrary offsets
// correct. Each wave: 1 output row quadrant, M=2 strips (32 px), full K,
// N=64 -> B-frag traffic halved vs M=1.
// ---------------------------------------------------------------------------
__global__ __launch_bounds__(512, 2)
void dcn_fused_kernel(const __half* __restrict__ xh,
                      const __half* __restrict__ wop,
                      const float* __restrict__ ob,
                      const __half* __restrict__ wpack,
                      const float* __restrict__ bias,
                      float* __restrict__ out) {
    int bid0 = blockIdx.x;
    int bid  = (bid0 & 7) * 32 + (bid0 >> 3);   // bijective XCD swizzle (256%8==0)
    int b = bid >> 6, rp = bid & 63;
    int ho0 = rp * 2;
    int tid = threadIdx.x;
    int w = tid >> 6, l = tid & 63;
    int p = l & 15, grp = l >> 4, grp16 = grp << 4;
    int r = w >> 2, q = w & 3;                  // output row (0/1), col quadrant
    int ho = ho0 + r;
    int wo0 = q * 32;                           // wave's 32-px segment

    __shared__ __align__(16) char  xs[131072];  // 8 rows x 128 px x 128 B
    __shared__ __half lomh[8][27][34];          // per-wave offset-conv results

    const char* xb = (const char*)xh + (size_t)b * HW * CIN * 2;

    // ---------------- stage the window (coalesced read, swizzled write) ----
#pragma unroll
    for (int it = 0; it < 16; ++it) {
        int idx = it * 512 + tid;               // 0..8191 16B-slots
        int rr = idx >> 10, c16 = idx & 1023;
        int col = c16 >> 3, sub = c16 & 7;
        int srow = min(max(ho0 - 3 + rr, 0), HH - 1);
        uint4 v = *(const uint4*)(xb + ((size_t)srow << 14) + (col << 7) + (sub << 4));
        *(uint4*)(xs + (((rr << 14) + (col << 7) + (sub << 4)) ^ ((col & 7) << 4))) = v;
    }
    __syncthreads();

    // ---------------- Phase 1: offset/mask conv from LDS -------------------
    {
        const uint4* wpo = (const uint4*)wop + l;
        int aad[2][9], asw[2][9];
        uint32_t avm[2][9];
#pragma unroll
        for (int m = 0; m < 2; ++m)
#pragma unroll
        for (int k = 0; k < 9; ++k) {
            int ki = k / 3, kj = k % 3;
            int hh = ho + ki - 1;
            int cr = wo0 + m * 16 + p + kj - 1;
            bool v = ((unsigned)hh < (unsigned)HH) && ((unsigned)cr < (unsigned)WW);
            int slot = r + ki + 2;              // always in [2,5]
            int cc = min(max(cr, 0), WW - 1);
            aad[m][k] = (slot << 14) + (cc << 7) + grp16;
            asw[m][k] = (cc & 7) << 4;
            avm[m][k] = v ? 0xffffffffu : 0u;
        }
        f32x4 oacc[2][2] = {};
#pragma unroll
        for (int t = 0; t < 18; ++t) {
            int k = t >> 1, half = t & 1;
            U4 a0, a1;
            a0.q = *(const uint4*)(xs + ((aad[0][k] + (half << 6)) ^ asw[0][k]));
            a1.q = *(const uint4*)(xs + ((aad[1][k] + (half << 6)) ^ asw[1][k]));
#pragma unroll
            for (int i = 0; i < 4; ++i) { a0.u[i] &= avm[0][k]; a1.u[i] &= avm[1][k]; }
            U4 b0, b1;
            b0.q = wpo[(t * 2 + 0) * 64];
            b1.q = wpo[(t * 2 + 1) * 64];
            oacc[0][0] = MFMA16(a0, b0, oacc[0][0]);
            oacc[0][1] = MFMA16(a0, b1, oacc[0][1]);
            oacc[1][0] = MFMA16(a1, b0, oacc[1][0]);
            oacc[1][1] = MFMA16(a1, b1, oacc[1][1]);
        }
        // D: col = lane&15 (= oc in tile), row = grp*4+i (= pixel in strip)
#pragma unroll
        for (int m = 0; m < 2; ++m)
#pragma unroll
        for (int nt = 0; nt < 2; ++nt) {
            int oc = nt * 16 + (l & 15);
            if (oc < 27) {
                float bv = ob[oc];
#pragma unroll
                for (int i = 0; i < 4; ++i) {
                    float vv = oacc[m][nt][i] + bv;
                    if (oc >= 18) vv = 1.f / (1.f + __expf(-vv));
                    lomh[w][oc][m * 16 + grp * 4 + i] = __float2half(vv);
                }
            }
        }
    }
    // lomh is wave-private: same-wave LDS RAW is ordered by lgkmcnt (compiler)

    // ---------------- Phase 2: deformable conv from LDS --------------------
    f32x4 acc[2][4] = {};
    const uint4* wpm = (const uint4*)wpack + l;

#pragma unroll
    for (int k = 0; k < 9; ++k) {
        int ch0[2], ch1[2], cw0[2], cw1[2];
        __half2 hwA[2], hwB[2], hwC[2], hwD[2];
        int okall = 1;
#pragma unroll
        for (int m = 0; m < 2; ++m) {
            int px = m * 16 + p;
            float dy = __half2float(lomh[w][k][px]);
            float dx = __half2float(lomh[w][9 + k][px]);
            float mk = __half2float(lomh[w][18 + k][px]);
            float hf = (float)(ho - 1 + k / 3) + dy;
            float wf = (float)(wo0 + px - 1 + k % 3) + dx;
            float h0f = floorf(hf), w0f = floorf(wf);
            float lh = hf - h0f, lw = wf - w0f;
            int h0 = (int)h0f, w0i = (int)w0f;
            int h1 = h0 + 1, w1i = w0i + 1;
            bool vh0 = (unsigned)h0 < (unsigned)HH, vh1 = (unsigned)h1 < (unsigned)HH;
            bool vw0 = (unsigned)w0i < (unsigned)WW, vw1 = (unsigned)w1i < (unsigned)WW;
            int c0 = min(max(h0, 0), HH - 1), c1 = min(max(h1, 0), HH - 1);
            int d0 = min(max(w0i, 0), WW - 1), d1 = min(max(w1i, 0), WW - 1);
            ch0[m] = c0; ch1[m] = c1; cw0[m] = d0; cw1[m] = d1;
            float fA = (vh0 && vw0) ? (1.f - lh) * (1.f - lw) * mk : 0.f;
            float fB = (vh0 && vw1) ? (1.f - lh) * lw * mk : 0.f;
            float fC = (vh1 && vw0) ? lh * (1.f - lw) * mk : 0.f;
            float fD = (vh1 && vw1) ? lh * lw * mk : 0.f;
            hwA[m] = __float2half2_rn(fA); hwB[m] = __float2half2_rn(fB);
            hwC[m] = __float2half2_rn(fC); hwD[m] = __float2half2_rn(fD);
            int s0 = c0 + 3 - ho0, s1 = c1 + 3 - ho0;
            okall &= (int)((unsigned)s0 <= 7u) & (int)((unsigned)s1 <= 7u);
        }
        int okw = __all(okall);

#pragma unroll
        for (int half = 0; half < 2; ++half) {
            int t = 2 * k + half;
            int hb = (half << 6) + grp16;
            U4 bf0, bf1, bf2, bf3;
            bf0.q = wpm[(t * 4 + 0) * 64];
            bf1.q = wpm[(t * 4 + 1) * 64];
            bf2.q = wpm[(t * 4 + 2) * 64];
            bf3.q = wpm[(t * 4 + 3) * 64];
            U4 a[2];
            if (okw) {
#pragma unroll
                for (int m = 0; m < 2; ++m) {
                    int s0 = ch0[m] + 3 - ho0, s1 = ch1[m] + 3 - ho0;
                    U4 u0, u1, u2, u3;
                    u0.q = *(const uint4*)(xs + (((s0 << 14) + (cw0[m] << 7) + hb) ^ ((cw0[m] & 7) << 4)));
                    u1.q = *(const uint4*)(xs + (((s0 << 14) + (cw1[m] << 7) + hb) ^ ((cw1[m] & 7) << 4)));
                    u2.q = *(const uint4*)(xs + (((s1 << 14) + (cw0[m] << 7) + hb) ^ ((cw0[m] & 7) << 4)));
                    u3.q = *(const uint4*)(xs + (((s1 << 14) + (cw1[m] << 7) + hb) ^ ((cw1[m] & 7) << 4)));
#pragma unroll
                    for (int i = 0; i < 4; ++i)
                        a[m].h2[i] = __hfma2(hwD[m], u3.h2[i],
                                     __hfma2(hwC[m], u2.h2[i],
                                     __hfma2(hwB[m], u1.h2[i],
                                     __hmul2(hwA[m], u0.h2[i]))));
                }
            } else {
#pragma unroll
                for (int m = 0; m < 2; ++m) {
                    U4 u0, u1, u2, u3;
                    u0.q = *(const uint4*)(xb + ((size_t)ch0[m] << 14) + (cw0[m] << 7) + hb);
                    u1.q = *(const uint4*)(xb + ((size_t)ch0[m] << 14) + (cw1[m] << 7) + hb);
                    u2.q = *(const uint4*)(xb + ((size_t)ch1[m] << 14) + (cw0[m] << 7) + hb);
                    u3.q = *(const uint4*)(xb + ((size_t)ch1[m] << 14) + (cw1[m] << 7) + hb);
#pragma unroll
                    for (int i = 0; i < 4; ++i)
                        a[m].h2[i] = __hfma2(hwD[m], u3.h2[i],
                                     __hfma2(hwC[m], u2.h2[i],
                                     __hfma2(hwB[m], u1.h2[i],
                                     __hmul2(hwA[m], u0.h2[i]))));
                }
            }
            acc[0][0] = MFMA16(a[0], bf0, acc[0][0]);
            acc[0][1] = MFMA16(a[0], bf1, acc[0][1]);
            acc[0][2] = MFMA16(a[0], bf2, acc[0][2]);
            acc[0][3] = MFMA16(a[0], bf3, acc[0][3]);
            acc[1][0] = MFMA16(a[1], bf0, acc[1][0]);
            acc[1][1] = MFMA16(a[1], bf1, acc[1][1]);
            acc[1][2] = MFMA16(a[1], bf2, acc[1][2]);
            acc[1][3] = MFMA16(a[1], bf3, acc[1][3]);
        }
    }

    // ---------------- Epilogue: D col = cout-in-tile, row = pixel ----------
#pragma unroll
    for (int m = 0; m < 2; ++m)
#pragma unroll
    for (int nt = 0; nt < 4; ++nt) {
        int oc = nt * 16 + (l & 15);
        float bv = bias[oc];
        f32x4 s;
#pragma unroll
        for (int i = 0; i < 4; ++i) s[i] = acc[m][nt][i] + bv;
        *(f32x4*)(out + ((size_t)(b * COUT + oc)) * HW + ho * WW + wo0 + m * 16 + grp * 4) = s;
    }
}

// ---------------------------------------------------------------------------
extern "C" void kernel_launch(void* const* d_in, const int* in_sizes, int n_in,
                              void* d_out, int out_size, void* d_ws, size_t ws_size,
                              hipStream_t stream) {
    const float* x    = (const float*)d_in[0];
    const float* wgt  = (const float*)d_in[1];
    const float* bias = (const float*)d_in[2];
    const float* ow   = (const float*)d_in[3];
    const float* ob   = (const float*)d_in[4];
    float* out = (float*)d_out;

    // workspace: wpack 73728B | wop 36864B | xh 8388608B
    char* ws = (char*)d_ws;
    __half* wpack = (__half*)ws;
    __half* wop   = (__half*)(ws + 73728);
    __half* xh    = (__half*)(ws + 73728 + 36864);

    prep_kernel<<<2048 + 216, 256, 0, stream>>>(x, wgt, ow, xh, wpack, wop);
    dcn_fused_kernel<<<B_ * HH / 2, 512, 0, stream>>>(xh, wop, ob, wpack, bias, out);
}

// Round 9
// 96.318 us; speedup vs baseline: 5.3046x; 1.0387x over previous
//
#include <hip/hip_runtime.h>
#include <hip/hip_fp16.h>

// DeformableConv2DLayer: B=4, Cin=64, H=W=128, Cout=64, 3x3, s=1, p=1, DG=1
#define B_   4
#define CIN  64
#define HH   128
#define WW   128
#define COUT 64
#define HW   (HH * WW)          // 16384
#define KK   9

typedef float    f32x4 __attribute__((ext_vector_type(4)));
typedef _Float16 f16x8 __attribute__((ext_vector_type(8)));

union U4 {
    uint4     q;
    uint32_t  u[4];
    __half2   h2[4];
    f16x8     v;
};

#define MFMA16(a, b, c) __builtin_amdgcn_mfma_f32_16x16x32_f16((a).v, (b).v, (c), 0, 0, 0)

// ---------------------------------------------------------------------------
// Prep kernel: weight packing only (x transpose folded into fused kernel).
// MFMA B-frag order: frag (t, nt); lane l holds o = nt*16+(l&15),
// K-elem r = t*32+(l>>4)*8+j, with r = tap*64 + c -> tap = r>>6, c = r&63.
// ---------------------------------------------------------------------------
__global__ __launch_bounds__(256)
void prep_kernel(const float* __restrict__ w,
                 const float* __restrict__ ow,
                 __half* __restrict__ wpack,
                 __half* __restrict__ wop) {
    int i = blockIdx.x * 256 + threadIdx.x;        // 0..55295
    if (i < 36864) {                               // main weights
        int j = i & 7, l = (i >> 3) & 63, s = i >> 9;  // s = t*4+nt
        int t = s >> 2;
        int rr = t * 32 + ((l >> 4) << 3) + j;
        int c = rr & 63, k = rr >> 6;
        int o = (s & 3) * 16 + (l & 15);
        wpack[i] = __float2half(w[(o * CIN + c) * KK + k]);
    } else {                                       // offset weights
        int i2 = i - 36864;                        // < 18432
        int j = i2 & 7, l = (i2 >> 3) & 63, s = i2 >> 9; // s = t*2+nt
        int t = s >> 1;
        int rr = t * 32 + ((l >> 4) << 3) + j;
        int c = rr & 63, k = rr >> 6;
        int o = (s & 1) * 16 + (l & 15);
        wop[i2] = __float2half((o < 27) ? ow[(o * CIN + c) * KK + k] : 0.f);
    }
}

// ---------------------------------------------------------------------------
// Fused DCN kernel. Block = 512 thr = 8 waves = 2 output rows x 128 cols.
// Stage: rows clamp(ho0-3 .. ho0+4) x 128 cols x 64ch read DIRECTLY from
// fp32 NCHW x (coalesced per channel-group), converted to fp16 and written
// NHWC-in-LDS with XOR swizzle. Phase 1 (offset conv) and phase 2 (bilinear
// + 64x576 matmul) both feed MFMA from LDS; rare out-of-window taps fall
// back to NCHW global gathers (wave-uniform branch).
// ---------------------------------------------------------------------------
__global__ __launch_bounds__(512, 2)
void dcn_fused_kernel(const float* __restrict__ x,
                      const __half* __restrict__ wop,
                      const float* __restrict__ ob,
                      const __half* __restrict__ wpack,
                      const float* __restrict__ bias,
                      float* __restrict__ out) {
    int bid0 = blockIdx.x;
    int bid  = (bid0 & 7) * 32 + (bid0 >> 3);   // bijective XCD swizzle (256%8==0)
    int b = bid >> 6, rp = bid & 63;
    int ho0 = rp * 2;
    int tid = threadIdx.x;
    int w = tid >> 6, l = tid & 63;
    int p = l & 15, grp = l >> 4, grp16 = grp << 4;
    int r = w >> 2, q = w & 3;                  // output row (0/1), col quadrant
    int ho = ho0 + r;
    int wo0 = q * 32;                           // wave's 32-px segment

    __shared__ __align__(16) char  xs[131072];  // 8 rows x 128 px x 128 B (fp16 NHWC)
    __shared__ __half lomh[8][27][34];          // per-wave offset-conv results

    const float* xbF = x + (size_t)b * CIN * HW;   // fp32 NCHW batch base

    // ------- stage window from NCHW fp32: convert + swizzled LDS write -----
#pragma unroll
    for (int it = 0; it < 16; ++it) {
        int cg  = it & 7;                       // 8-channel group
        int pix = (it >> 3) * 512 + tid;        // 0..1023 window pixel
        int rr = pix >> 7, col = pix & 127;
        int srow = min(max(ho0 - 3 + rr, 0), HH - 1);
        const float* xp = xbF + (size_t)(cg * 8) * HW + srow * WW + col;
        uint32_t u[4];
#pragma unroll
        for (int j = 0; j < 4; ++j) {
            __half2 h = __floats2half2_rn(xp[(size_t)(2 * j) * HW],
                                          xp[(size_t)(2 * j + 1) * HW]);
            u[j] = *(uint32_t*)&h;
        }
        *(uint4*)(xs + (((rr << 14) + (col << 7) + (cg << 4)) ^ ((col & 7) << 4)))
            = *(const uint4*)u;
    }
    __syncthreads();

    // ---------------- Phase 1: offset/mask conv from LDS -------------------
    {
        const uint4* wpo = (const uint4*)wop + l;
        int aad[2][9], asw[2][9];
        uint32_t avm[2][9];
#pragma unroll
        for (int m = 0; m < 2; ++m)
#pragma unroll
        for (int k = 0; k < 9; ++k) {
            int ki = k / 3, kj = k % 3;
            int hh = ho + ki - 1;
            int cr = wo0 + m * 16 + p + kj - 1;
            bool v = ((unsigned)hh < (unsigned)HH) && ((unsigned)cr < (unsigned)WW);
            int slot = r + ki + 2;              // always in [2,5]
            int cc = min(max(cr, 0), WW - 1);
            aad[m][k] = (slot << 14) + (cc << 7) + grp16;
            asw[m][k] = (cc & 7) << 4;
            avm[m][k] = v ? 0xffffffffu : 0u;
        }
        f32x4 oacc[2][2] = {};
#pragma unroll
        for (int t = 0; t < 18; ++t) {
            int k = t >> 1, half = t & 1;
            U4 a0, a1;
            a0.q = *(const uint4*)(xs + ((aad[0][k] + (half << 6)) ^ asw[0][k]));
            a1.q = *(const uint4*)(xs + ((aad[1][k] + (half << 6)) ^ asw[1][k]));
#pragma unroll
            for (int i = 0; i < 4; ++i) { a0.u[i] &= avm[0][k]; a1.u[i] &= avm[1][k]; }
            U4 b0, b1;
            b0.q = wpo[(t * 2 + 0) * 64];
            b1.q = wpo[(t * 2 + 1) * 64];
            oacc[0][0] = MFMA16(a0, b0, oacc[0][0]);
            oacc[0][1] = MFMA16(a0, b1, oacc[0][1]);
            oacc[1][0] = MFMA16(a1, b0, oacc[1][0]);
            oacc[1][1] = MFMA16(a1, b1, oacc[1][1]);
        }
        // D: col = lane&15 (= oc in tile), row = grp*4+i (= pixel in strip)
#pragma unroll
        for (int m = 0; m < 2; ++m)
#pragma unroll
        for (int nt = 0; nt < 2; ++nt) {
            int oc = nt * 16 + (l & 15);
            if (oc < 27) {
                float bv = ob[oc];
#pragma unroll
                for (int i = 0; i < 4; ++i) {
                    float vv = oacc[m][nt][i] + bv;
                    if (oc >= 18) vv = 1.f / (1.f + __expf(-vv));
                    lomh[w][oc][m * 16 + grp * 4 + i] = __float2half(vv);
                }
            }
        }
    }
    // lomh is wave-private: same-wave LDS RAW ordered by lgkmcnt (compiler)

    // ---------------- Phase 2: deformable conv from LDS --------------------
    f32x4 acc[2][4] = {};
    const uint4* wpm = (const uint4*)wpack + l;

#pragma unroll
    for (int k = 0; k < 9; ++k) {
        int ch0[2], ch1[2], cw0[2], cw1[2];
        __half2 hwA[2], hwB[2], hwC[2], hwD[2];
        int okall = 1;
#pragma unroll
        for (int m = 0; m < 2; ++m) {
            int px = m * 16 + p;
            float dy = __half2float(lomh[w][k][px]);
            float dx = __half2float(lomh[w][9 + k][px]);
            float mk = __half2float(lomh[w][18 + k][px]);
            float hf = (float)(ho - 1 + k / 3) + dy;
            float wf = (float)(wo0 + px - 1 + k % 3) + dx;
            float h0f = floorf(hf), w0f = floorf(wf);
            float lh = hf - h0f, lw = wf - w0f;
            int h0 = (int)h0f, w0i = (int)w0f;
            int h1 = h0 + 1, w1i = w0i + 1;
            bool vh0 = (unsigned)h0 < (unsigned)HH, vh1 = (unsigned)h1 < (unsigned)HH;
            bool vw0 = (unsigned)w0i < (unsigned)WW, vw1 = (unsigned)w1i < (unsigned)WW;
            int c0 = min(max(h0, 0), HH - 1), c1 = min(max(h1, 0), HH - 1);
            int d0 = min(max(w0i, 0), WW - 1), d1 = min(max(w1i, 0), WW - 1);
            ch0[m] = c0; ch1[m] = c1; cw0[m] = d0; cw1[m] = d1;
            float fA = (vh0 && vw0) ? (1.f - lh) * (1.f - lw) * mk : 0.f;
            float fB = (vh0 && vw1) ? (1.f - lh) * lw * mk : 0.f;
            float fC = (vh1 && vw0) ? lh * (1.f - lw) * mk : 0.f;
            float fD = (vh1 && vw1) ? lh * lw * mk : 0.f;
            hwA[m] = __float2half2_rn(fA); hwB[m] = __float2half2_rn(fB);
            hwC[m] = __float2half2_rn(fC); hwD[m] = __float2half2_rn(fD);
            int s0 = c0 + 3 - ho0, s1 = c1 + 3 - ho0;
            okall &= (int)((unsigned)s0 <= 7u) & (int)((unsigned)s1 <= 7u);
        }
        int okw = __all(okall);

#pragma unroll
        for (int half = 0; half < 2; ++half) {
            int t = 2 * k + half;
            int hb = (half << 6) + grp16;
            U4 bf0, bf1, bf2, bf3;
            bf0.q = wpm[(t * 4 + 0) * 64];
            bf1.q = wpm[(t * 4 + 1) * 64];
            bf2.q = wpm[(t * 4 + 2) * 64];
            bf3.q = wpm[(t * 4 + 3) * 64];
            U4 a[2];
            if (okw) {
#pragma unroll
                for (int m = 0; m < 2; ++m) {
                    int s0 = ch0[m] + 3 - ho0, s1 = ch1[m] + 3 - ho0;
                    U4 u0, u1, u2, u3;
                    u0.q = *(const uint4*)(xs + (((s0 << 14) + (cw0[m] << 7) + hb) ^ ((cw0[m] & 7) << 4)));
                    u1.q = *(const uint4*)(xs + (((s0 << 14) + (cw1[m] << 7) + hb) ^ ((cw1[m] & 7) << 4)));
                    u2.q = *(const uint4*)(xs + (((s1 << 14) + (cw0[m] << 7) + hb) ^ ((cw0[m] & 7) << 4)));
                    u3.q = *(const uint4*)(xs + (((s1 << 14) + (cw1[m] << 7) + hb) ^ ((cw1[m] & 7) << 4)));
#pragma unroll
                    for (int i = 0; i < 4; ++i)
                        a[m].h2[i] = __hfma2(hwD[m], u3.h2[i],
                                     __hfma2(hwC[m], u2.h2[i],
                                     __hfma2(hwB[m], u1.h2[i],
                                     __hmul2(hwA[m], u0.h2[i]))));
                }
            } else {
                // rare fallback: gather 8 channels per corner from fp32 NCHW
                const float* cbase = xbF + (size_t)(32 * half + grp * 8) * HW;
#pragma unroll
                for (int m = 0; m < 2; ++m) {
                    U4 u0, u1, u2, u3;
#pragma unroll
                    for (int j = 0; j < 4; ++j) {
                        const float* p0 = cbase + (size_t)(2 * j) * HW;
                        const float* p1 = cbase + (size_t)(2 * j + 1) * HW;
                        int i00 = ch0[m] * WW + cw0[m], i01 = ch0[m] * WW + cw1[m];
                        int i10 = ch1[m] * WW + cw0[m], i11 = ch1[m] * WW + cw1[m];
                        __half2 h;
                        h = __floats2half2_rn(p0[i00], p1[i00]); u0.u[j] = *(uint32_t*)&h;
                        h = __floats2half2_rn(p0[i01], p1[i01]); u1.u[j] = *(uint32_t*)&h;
                        h = __floats2half2_rn(p0[i10], p1[i10]); u2.u[j] = *(uint32_t*)&h;
                        h = __floats2half2_rn(p0[i11], p1[i11]); u3.u[j] = *(uint32_t*)&h;
                    }
#pragma unroll
                    for (int i = 0; i < 4; ++i)
                        a[m].h2[i] = __hfma2(hwD[m], u3.h2[i],
                                     __hfma2(hwC[m], u2.h2[i],
                                     __hfma2(hwB[m], u1.h2[i],
                                     __hmul2(hwA[m], u0.h2[i]))));
                }
            }
            acc[0][0] = MFMA16(a[0], bf0, acc[0][0]);
            acc[0][1] = MFMA16(a[0], bf1, acc[0][1]);
            acc[0][2] = MFMA16(a[0], bf2, acc[0][2]);
            acc[0][3] = MFMA16(a[0], bf3, acc[0][3]);
            acc[1][0] = MFMA16(a[1], bf0, acc[1][0]);
            acc[1][1] = MFMA16(a[1], bf1, acc[1][1]);
            acc[1][2] = MFMA16(a[1], bf2, acc[1][2]);
            acc[1][3] = MFMA16(a[1], bf3, acc[1][3]);
        }
    }

    // ---------------- Epilogue: D col = cout-in-tile, row = pixel ----------
#pragma unroll
    for (int m = 0; m < 2; ++m)
#pragma unroll
    for (int nt = 0; nt < 4; ++nt) {
        int oc = nt * 16 + (l & 15);
        float bv = bias[oc];
        f32x4 s;
#pragma unroll
        for (int i = 0; i < 4; ++i) s[i] = acc[m][nt][i] + bv;
        *(f32x4*)(out + ((size_t)(b * COUT + oc)) * HW + ho * WW + wo0 + m * 16 + grp * 4) = s;
    }
}

// ---------------------------------------------------------------------------
extern "C" void kernel_launch(void* const* d_in, const int* in_sizes, int n_in,
                              void* d_out, int out_size, void* d_ws, size_t ws_size,
                              hipStream_t stream) {
    const float* x    = (const float*)d_in[0];
    const float* wgt  = (const float*)d_in[1];
    const float* bias = (const float*)d_in[2];
    const float* ow   = (const float*)d_in[3];
    const float* ob   = (const float*)d_in[4];
    float* out = (float*)d_out;

    // workspace: wpack 73728B | wop 36864B
    char* ws = (char*)d_ws;
    __half* wpack = (__half*)ws;
    __half* wop   = (__half*)(ws + 73728);

    prep_kernel<<<216, 256, 0, stream>>>(wgt, ow, wpack, wop);
    dcn_fused_kernel<<<B_ * HH / 2, 512, 0, stream>>>(x, wop, ob, wpack, bias, out);
}